// Round 11
// baseline (106.829 us; speedup 1.0000x reference)
//
#include <hip/hip_runtime.h>

// VQ color lookup, round 9: explicit DS software pipeline.
// R8 idle ~19 µs diagnosed as ds_read convoying (all waves wait together).
// Fix: asm prefetch block reads the NEXT 2-pair group (8x ds_read_b64) ~230
// VALU-cycles before the asm compute block consumes it; compute starts with
// s_waitcnt lgkmcnt(8) (waits only the OLDER 8 reads — fine-grained, never
// drains the in-flight prefetch). Ping-pong C/N reg buffers, rolled loop.
// Epilogue reuses ZA/ZB regs instead of re-reading z (FETCH was 2x).
// Numerics: identical halved-distance sequence (contract-off, left-assoc,
// op_sel broadcasts) as R6-R8 -> bit-identical to numpy. All rounds absmax 0.0.

#define KPAL 512
#define HW   65536            // 256*256
#define CHW  (3 * HW)
#define NPIX (8 * HW)         // 524288 pixels
#define NELEM (NPIX * 3)      // 1572864 output color elements
#define NWAVE 4
#define PPT   4               // pixels per thread (64 lanes * 4 = 256 px/block)

typedef float f2 __attribute__((ext_vector_type(2)));

struct __align__(32) Pair { f2 x, y, z, w; };  // w = 0.5*||t||^2 (exact halve)

// One palette pair (entries 2p lo / 2p+1 hi) vs 4 pixels, 28 v_pk ops.
// Per px: r=z0*cx; t=z1*cy; r+=t; t=z2*cz; r+=t; r=hz-r; r+=ht2.
#define PAIR_BODY \
    "v_pk_mul_f32 %[r0], %[A0], %[cx] op_sel:[0,0] op_sel_hi:[0,1]\n\t" \
    "v_pk_mul_f32 %[r1], %[A1], %[cx] op_sel:[0,0] op_sel_hi:[0,1]\n\t" \
    "v_pk_mul_f32 %[r2], %[A2], %[cx] op_sel:[0,0] op_sel_hi:[0,1]\n\t" \
    "v_pk_mul_f32 %[r3], %[A3], %[cx] op_sel:[0,0] op_sel_hi:[0,1]\n\t" \
    "v_pk_mul_f32 %[t0], %[A0], %[cy] op_sel:[1,0] op_sel_hi:[1,1]\n\t" \
    "v_pk_mul_f32 %[t1], %[A1], %[cy] op_sel:[1,0] op_sel_hi:[1,1]\n\t" \
    "v_pk_mul_f32 %[t2], %[A2], %[cy] op_sel:[1,0] op_sel_hi:[1,1]\n\t" \
    "v_pk_mul_f32 %[t3], %[A3], %[cy] op_sel:[1,0] op_sel_hi:[1,1]\n\t" \
    "v_pk_add_f32 %[r0], %[r0], %[t0]\n\t" \
    "v_pk_add_f32 %[r1], %[r1], %[t1]\n\t" \
    "v_pk_add_f32 %[r2], %[r2], %[t2]\n\t" \
    "v_pk_add_f32 %[r3], %[r3], %[t3]\n\t" \
    "v_pk_mul_f32 %[t0], %[B0], %[cz] op_sel:[0,0] op_sel_hi:[0,1]\n\t" \
    "v_pk_mul_f32 %[t1], %[B1], %[cz] op_sel:[0,0] op_sel_hi:[0,1]\n\t" \
    "v_pk_mul_f32 %[t2], %[B2], %[cz] op_sel:[0,0] op_sel_hi:[0,1]\n\t" \
    "v_pk_mul_f32 %[t3], %[B3], %[cz] op_sel:[0,0] op_sel_hi:[0,1]\n\t" \
    "v_pk_add_f32 %[r0], %[r0], %[t0]\n\t" \
    "v_pk_add_f32 %[r1], %[r1], %[t1]\n\t" \
    "v_pk_add_f32 %[r2], %[r2], %[t2]\n\t" \
    "v_pk_add_f32 %[r3], %[r3], %[t3]\n\t" \
    "v_pk_add_f32 %[r0], %[B0], %[r0] op_sel:[1,0] op_sel_hi:[1,1] neg_lo:[0,1] neg_hi:[0,1]\n\t" \
    "v_pk_add_f32 %[r1], %[B1], %[r1] op_sel:[1,0] op_sel_hi:[1,1] neg_lo:[0,1] neg_hi:[0,1]\n\t" \
    "v_pk_add_f32 %[r2], %[B2], %[r2] op_sel:[1,0] op_sel_hi:[1,1] neg_lo:[0,1] neg_hi:[0,1]\n\t" \
    "v_pk_add_f32 %[r3], %[B3], %[r3] op_sel:[1,0] op_sel_hi:[1,1] neg_lo:[0,1] neg_hi:[0,1]\n\t" \
    "v_pk_add_f32 %[r0], %[r0], %[cw]\n\t" \
    "v_pk_add_f32 %[r1], %[r1], %[cw]\n\t" \
    "v_pk_add_f32 %[r2], %[r2], %[cw]\n\t" \
    "v_pk_add_f32 %[r3], %[r3], %[cw]"

#define PAIR_OPS(R, T, CX, CY, CZ, CW) \
    : [r0] "=&v"(R[0]), [r1] "=&v"(R[1]), [r2] "=&v"(R[2]), [r3] "=&v"(R[3]), \
      [t0] "=&v"(T[0]), [t1] "=&v"(T[1]), [t2] "=&v"(T[2]), [t3] "=&v"(T[3])  \
    : [A0] "v"(ZA[0]), [A1] "v"(ZA[1]), [A2] "v"(ZA[2]), [A3] "v"(ZA[3]),     \
      [B0] "v"(ZB[0]), [B1] "v"(ZB[1]), [B2] "v"(ZB[2]), [B3] "v"(ZB[3]),     \
      [cx] "v"(CX), [cy] "v"(CY), [cz] "v"(CZ), [cw] "v"(CW)

// waits only the OLDER 8 ds_reads (current prefetch's 8 stay in flight)
#define PAIR_WAIT(R, T, CX, CY, CZ, CW) \
    asm volatile("s_waitcnt lgkmcnt(8)\n\t" PAIR_BODY PAIR_OPS(R, T, CX, CY, CZ, CW))
#define PAIR_NOWAIT(R, T, CX, CY, CZ, CW) \
    asm volatile(PAIR_BODY PAIR_OPS(R, T, CX, CY, CZ, CW))

#define PREFETCH(G, AD) \
    asm volatile("ds_read_b64 %[n0], %[ad]\n\t"           \
                 "ds_read_b64 %[n1], %[ad] offset:8\n\t"  \
                 "ds_read_b64 %[n2], %[ad] offset:16\n\t" \
                 "ds_read_b64 %[n3], %[ad] offset:24\n\t" \
                 "ds_read_b64 %[n4], %[ad] offset:32\n\t" \
                 "ds_read_b64 %[n5], %[ad] offset:40\n\t" \
                 "ds_read_b64 %[n6], %[ad] offset:48\n\t" \
                 "ds_read_b64 %[n7], %[ad] offset:56\n\t" \
                 "v_add_u32 %[ad], 64, %[ad]"             \
                 : [n0] "=&v"(G[0]), [n1] "=&v"(G[1]), [n2] "=&v"(G[2]), \
                   [n3] "=&v"(G[3]), [n4] "=&v"(G[4]), [n5] "=&v"(G[5]), \
                   [n6] "=&v"(G[6]), [n7] "=&v"(G[7]), [ad] "+v"(AD))

#define SEL(R, PJ) do {                                            \
    _Pragma("unroll")                                              \
    for (int i = 0; i < PPT; ++i) {                                \
        const float mn = fminf(fminf(best[i], R[i].x), R[i].y);    \
        bj[i] = (mn < best[i]) ? (PJ) : bj[i];                     \
        best[i] = mn;                                              \
    } } while (0)

__global__ __launch_bounds__(256, 6)
void vq_kernel(const float* __restrict__ z,
               const float* __restrict__ table,
               float* __restrict__ out,
               float* __restrict__ loss)
{
    __shared__ Pair  stab[KPAL / 2];        // MUST be first: prefetch overrun
    __shared__ float cb_best[NWAVE][256];   // lands here (harmless, unused)
    __shared__ int   cb_bi[NWAVE][256];
    __shared__ float wsum[NWAVE];
    const int t = threadIdx.x;
    const int w = t >> 6, lane = t & 63;

    // Stage palette pairs into LDS.
    {
        const int j = t;
        const float a0 = table[6 * j + 0], a1 = table[6 * j + 1], a2 = table[6 * j + 2];
        const float b0 = table[6 * j + 3], b1 = table[6 * j + 4], b2 = table[6 * j + 5];
        float aw, bw;
        {
#pragma clang fp contract(off)
            aw = a0 * a0 + a1 * a1 + a2 * a2;
            bw = b0 * b0 + b1 * b1 + b2 * b2;
        }
        Pair p;
        p.x = (f2){a0, b0};
        p.y = (f2){a1, b1};
        p.z = (f2){a2, b2};
        p.w = (f2){0.5f * aw, 0.5f * bw};
        stab[j] = p;
    }
    __syncthreads();

    // Block = 256 px; all 4 waves scan the same px against their own quarter.
    const int blockbase = blockIdx.x * 256;
    const int b  = blockbase >> 16;
    const int p0 = blockbase & (HW - 1);
    const int base0 = b * CHW + p0 + lane;

    f2 ZA[PPT], ZB[PPT];                    // (z0,z1), (z2, 0.5*||z||^2)
#pragma unroll
    for (int i = 0; i < PPT; ++i) {
        const int base = base0 + 64 * i;
        const float z0 = z[base];
        const float z1 = z[base + HW];
        const float z2 = z[base + 2 * HW];
        float zs;
        {
#pragma clang fp contract(off)
            zs = z0 * z0 + z1 * z1 + z2 * z2;
        }
        ZA[i] = (f2){z0, z1};
        ZB[i] = (f2){z2, 0.5f * zs};
    }

    float best[PPT];
    int   bj[PPT];                          // global pair index
#pragma unroll
    for (int i = 0; i < PPT; ++i) { best[i] = 3.4e38f; bj[i] = w * 64; }

    // Software pipeline: groups of 2 pairs; prefetch runs one group ahead.
    f2* sf = (f2*)stab;                     // pair p = sf[4p .. 4p+3]
    f2 C[8], N[8];
#pragma unroll
    for (int q = 0; q < 8; ++q) C[q] = sf[w * 256 + q];   // group 0 preload
    unsigned ad = (unsigned)(size_t)(&sf[w * 256 + 8]);   // -> group 1
    int pj = w * 64;

#pragma unroll 1
    for (int it = 0; it < 16; ++it) {
        f2 R[PPT], T[PPT];
        PREFETCH(N, ad);                    // pairs pj+2, pj+3
        PAIR_WAIT(R, T, C[0], C[1], C[2], C[3]);
        SEL(R, pj);
        PAIR_NOWAIT(R, T, C[4], C[5], C[6], C[7]);
        SEL(R, pj + 1);
        PREFETCH(C, ad);                    // pairs pj+4, pj+5
        PAIR_WAIT(R, T, N[0], N[1], N[2], N[3]);
        SEL(R, pj + 2);
        PAIR_NOWAIT(R, T, N[4], N[5], N[6], N[7]);
        SEL(R, pj + 3);
        pj += 4;
    }

    // Resolve lo/hi within winning pair (exact lo recompute), publish.
#pragma unroll
    for (int i = 0; i < PPT; ++i) {
        const Pair cc = stab[bj[i]];
        float dx;
        {
#pragma clang fp contract(off)
            float m = ZA[i].x * cc.x.x;
            m = m + ZA[i].y * cc.y.x;
            m = m + ZB[i].x * cc.z.x;
            float s = ZB[i].y - m;
            dx = s + cc.w.x;
        }
        const int bi = (dx == best[i]) ? 2 * bj[i] : 2 * bj[i] + 1;
        cb_best[w][lane + 64 * i] = best[i];
        cb_bi[w][lane + 64 * i]   = bi;
    }
    __syncthreads();

    // Combine quarters (ordered strict < => numpy first-index), write, loss.
    // px p = t was scanned by THIS thread at slot i == w: reuse regs, no z re-read.
    f2 zA = ZA[0], zB = ZB[0];
    if (w == 1)      { zA = ZA[1]; zB = ZB[1]; }
    else if (w == 2) { zA = ZA[2]; zB = ZB[2]; }
    else if (w == 3) { zA = ZA[3]; zB = ZB[3]; }

    float lsum = 0.0f;
    {
        const int p = t;
        float bb = cb_best[0][p];
        int   kk = cb_bi[0][p];
#pragma unroll
        for (int ww = 1; ww < NWAVE; ++ww) {
            const float d  = cb_best[ww][p];
            const int   k2 = cb_bi[ww][p];
            if (d < bb) { bb = d; kk = k2; }
        }
        const int base = b * CHW + p0 + p;
        const float c0 = table[3 * kk + 0];
        const float c1 = table[3 * kk + 1];
        const float c2 = table[3 * kk + 2];
        out[base]          = c0;
        out[base + HW]     = c1;
        out[base + 2 * HW] = c2;
        const float e0 = c0 - zA.x, e1 = c1 - zA.y, e2 = c2 - zB.x;
        lsum = e0 * e0 + e1 * e1 + e2 * e2;
    }

    for (int off = 32; off > 0; off >>= 1)
        lsum += __shfl_down(lsum, off);

    if ((t & 63) == 0) wsum[w] = lsum;
    __syncthreads();
    if (t == 0) {
        const float s = wsum[0] + wsum[1] + wsum[2] + wsum[3];
        atomicAdd(loss, s * (11.0f / (float)NELEM));
    }
}

extern "C" void kernel_launch(void* const* d_in, const int* in_sizes, int n_in,
                              void* d_out, int out_size, void* d_ws, size_t ws_size,
                              hipStream_t stream)
{
    const float* z     = (const float*)d_in[0];
    const float* table = (const float*)d_in[1];
    float* out  = (float*)d_out;
    float* loss = out + NELEM;

    hipMemsetAsync(loss, 0, sizeof(float), stream);
    vq_kernel<<<NPIX / 256, 256, 0, stream>>>(z, table, out, loss);
}

// Round 12
// 103.065 us; speedup vs baseline: 1.0365x; 1.0365x over previous
//
#include <hip/hip_runtime.h>

// VQ color lookup, round 10: R8 structure, spill removed.
// R8/R9 post-mortem: FETCH/WRITE_SIZE inflation (6.5/14.4 and 10.8/24.5 MB
// vs 3.1/6.2 clean) = scratch spill traffic from the launch_bounds VGPR caps
// ((256,8)->64, (256,6)->85). The R9 pipeline was neutralized by spill
// round-trips. Fix: __launch_bounds__(256,4) -> 128-VGPR budget, live set
// ~55 -> no spill; grid still gives 8 blocks/CU, LDS 16.4 KB allows 9.
// Epilogue reuses ZA/ZB regs (px t scanned by this thread at slot i==w) —
// no z re-read. Everything else identical to R8 (split-K quarters, op_sel
// packed asm, min3 select, exact lo-recompute tie resolve).
// Numerics bit-identical to numpy (halved distance, contract-off,
// left-assoc). R1-R9 all passed absmax 0.0.

#define KPAL 512
#define HW   65536            // 256*256
#define CHW  (3 * HW)
#define NPIX (8 * HW)         // 524288 pixels
#define NELEM (NPIX * 3)      // 1572864 output color elements
#define PPT   4               // pixels per thread (64 lanes * 4 = 256 px/block)
#define NWAVE 4
#define PAIRS_PER_WAVE (KPAL / 2 / NWAVE)   // 64

typedef float f2 __attribute__((ext_vector_type(2)));

struct __align__(32) Pair {   // palette entries 2j (lo half) and 2j+1 (hi)
    f2 x, y, z, w;            // w = 0.5 * ||t||^2 (contract-off, exact halve)
};

// 4 pixels x 1 palette pair, halved distance, numpy-exact order:
//   d = z0*cx; d += z1*cy; d += z2*cz (cross); d = hz - d; d += ht2
// ZA = (z0, z1), ZB = (z2, hz); op_sel broadcasts the needed half.
static __device__ __forceinline__ void quad_dist(
    f2 cx, f2 cy, f2 cz, f2 cw,
    f2 A0, f2 B0, f2 A1, f2 B1, f2 A2, f2 B2, f2 A3, f2 B3,
    f2& r0, f2& r1, f2& r2, f2& r3)
{
    f2 d0, d1, d2, d3, t0, t1, t2, t3;
    asm("v_pk_mul_f32 %[d0], %[A0], %[cx] op_sel:[0,0] op_sel_hi:[0,1]\n\t"
        "v_pk_mul_f32 %[d1], %[A1], %[cx] op_sel:[0,0] op_sel_hi:[0,1]\n\t"
        "v_pk_mul_f32 %[d2], %[A2], %[cx] op_sel:[0,0] op_sel_hi:[0,1]\n\t"
        "v_pk_mul_f32 %[d3], %[A3], %[cx] op_sel:[0,0] op_sel_hi:[0,1]\n\t"
        "v_pk_mul_f32 %[t0], %[A0], %[cy] op_sel:[1,0] op_sel_hi:[1,1]\n\t"
        "v_pk_mul_f32 %[t1], %[A1], %[cy] op_sel:[1,0] op_sel_hi:[1,1]\n\t"
        "v_pk_mul_f32 %[t2], %[A2], %[cy] op_sel:[1,0] op_sel_hi:[1,1]\n\t"
        "v_pk_mul_f32 %[t3], %[A3], %[cy] op_sel:[1,0] op_sel_hi:[1,1]\n\t"
        "v_pk_add_f32 %[d0], %[d0], %[t0]\n\t"
        "v_pk_add_f32 %[d1], %[d1], %[t1]\n\t"
        "v_pk_add_f32 %[d2], %[d2], %[t2]\n\t"
        "v_pk_add_f32 %[d3], %[d3], %[t3]\n\t"
        "v_pk_mul_f32 %[t0], %[B0], %[cz] op_sel:[0,0] op_sel_hi:[0,1]\n\t"
        "v_pk_mul_f32 %[t1], %[B1], %[cz] op_sel:[0,0] op_sel_hi:[0,1]\n\t"
        "v_pk_mul_f32 %[t2], %[B2], %[cz] op_sel:[0,0] op_sel_hi:[0,1]\n\t"
        "v_pk_mul_f32 %[t3], %[B3], %[cz] op_sel:[0,0] op_sel_hi:[0,1]\n\t"
        "v_pk_add_f32 %[d0], %[d0], %[t0]\n\t"
        "v_pk_add_f32 %[d1], %[d1], %[t1]\n\t"
        "v_pk_add_f32 %[d2], %[d2], %[t2]\n\t"
        "v_pk_add_f32 %[d3], %[d3], %[t3]\n\t"
        "v_pk_add_f32 %[d0], %[B0], %[d0] op_sel:[1,0] op_sel_hi:[1,1] neg_lo:[0,1] neg_hi:[0,1]\n\t"
        "v_pk_add_f32 %[d1], %[B1], %[d1] op_sel:[1,0] op_sel_hi:[1,1] neg_lo:[0,1] neg_hi:[0,1]\n\t"
        "v_pk_add_f32 %[d2], %[B2], %[d2] op_sel:[1,0] op_sel_hi:[1,1] neg_lo:[0,1] neg_hi:[0,1]\n\t"
        "v_pk_add_f32 %[d3], %[B3], %[d3] op_sel:[1,0] op_sel_hi:[1,1] neg_lo:[0,1] neg_hi:[0,1]\n\t"
        "v_pk_add_f32 %[d0], %[d0], %[cw]\n\t"
        "v_pk_add_f32 %[d1], %[d1], %[cw]\n\t"
        "v_pk_add_f32 %[d2], %[d2], %[cw]\n\t"
        "v_pk_add_f32 %[d3], %[d3], %[cw]"
        : [d0] "=&v"(d0), [d1] "=&v"(d1), [d2] "=&v"(d2), [d3] "=&v"(d3),
          [t0] "=&v"(t0), [t1] "=&v"(t1), [t2] "=&v"(t2), [t3] "=&v"(t3)
        : [A0] "v"(A0), [B0] "v"(B0), [A1] "v"(A1), [B1] "v"(B1),
          [A2] "v"(A2), [B2] "v"(B2), [A3] "v"(A3), [B3] "v"(B3),
          [cx] "v"(cx), [cy] "v"(cy), [cz] "v"(cz), [cw] "v"(cw));
    r0 = d0; r1 = d1; r2 = d2; r3 = d3;
}

__global__ __launch_bounds__(256, 4)
void vq_kernel(const float* __restrict__ z,
               const float* __restrict__ table,
               float* __restrict__ out,
               float* __restrict__ loss)
{
    __shared__ Pair  stab[KPAL / 2];        // 8 KB
    __shared__ float cb_best[NWAVE][256];   // 4 KB
    __shared__ int   cb_bi[NWAVE][256];     // 4 KB
    __shared__ float wsum[NWAVE];
    const int t = threadIdx.x;
    const int w = t >> 6, lane = t & 63;

    // Stage palette pairs into LDS.
    {
        const int j = t;
        const float a0 = table[6 * j + 0], a1 = table[6 * j + 1], a2 = table[6 * j + 2];
        const float b0 = table[6 * j + 3], b1 = table[6 * j + 4], b2 = table[6 * j + 5];
        float aw, bw;
        {
#pragma clang fp contract(off)
            aw = a0 * a0 + a1 * a1 + a2 * a2;
            bw = b0 * b0 + b1 * b1 + b2 * b2;
        }
        Pair p;
        p.x = (f2){a0, b0};
        p.y = (f2){a1, b1};
        p.z = (f2){a2, b2};
        p.w = (f2){0.5f * aw, 0.5f * bw};   // exact
        stab[j] = p;
    }
    __syncthreads();

    // Block covers 256 consecutive pixels; all 4 waves process the same px.
    const int blockbase = blockIdx.x * 256;
    const int b  = blockbase >> 16;           // blocks never straddle batch
    const int p0 = blockbase & (HW - 1);
    const int base0 = b * CHW + p0 + lane;    // pixel i at base0 + 64*i

    f2 ZA[PPT], ZB[PPT];                      // (z0,z1), (z2, 0.5*||z||^2)
#pragma unroll
    for (int i = 0; i < PPT; ++i) {
        const int base = base0 + 64 * i;
        const float z0 = z[base];
        const float z1 = z[base + HW];
        const float z2 = z[base + 2 * HW];
        float zs;
        {
#pragma clang fp contract(off)
            zs = z0 * z0 + z1 * z1 + z2 * z2;
        }
        ZA[i] = (f2){z0, z1};
        ZB[i] = (f2){z2, 0.5f * zs};          // exact halve
    }

    float best[PPT];
    int   bj[PPT];                            // global pair index
#pragma unroll
    for (int i = 0; i < PPT; ++i) { best[i] = 3.4e38f; bj[i] = w * PAIRS_PER_WAVE; }

    // Wave w scans its palette quarter for all 4 px.
#pragma unroll 2
    for (int jj = 0; jj < PAIRS_PER_WAVE; ++jj) {
        const int jg = w * PAIRS_PER_WAVE + jj;
        const Pair c = stab[jg];              // uniform -> ds broadcast
        f2 r[PPT];
        quad_dist(c.x, c.y, c.z, c.w,
                  ZA[0], ZB[0], ZA[1], ZB[1], ZA[2], ZB[2], ZA[3], ZB[3],
                  r[0], r[1], r[2], r[3]);
#pragma unroll
        for (int i = 0; i < PPT; ++i) {
            const float mn = fminf(fminf(best[i], r[i].x), r[i].y); // v_min3
            const bool imp = mn < best[i];
            bj[i] = imp ? jg : bj[i];
            best[i] = mn;
        }
    }

    // Resolve lo/hi within the winning pair (exact lo recompute), publish.
#pragma unroll
    for (int i = 0; i < PPT; ++i) {
        const Pair cc = stab[bj[i]];
        float dx;
        {
#pragma clang fp contract(off)
            float m = ZA[i].x * cc.x.x;       // z0*cx
            m = m + ZA[i].y * cc.y.x;         // + z1*cy
            m = m + ZB[i].x * cc.z.x;         // + z2*cz
            float s = ZB[i].y - m;            // hz - cross
            dx = s + cc.w.x;                  // + ht2
        }
        const int bi = (dx == best[i]) ? 2 * bj[i] : 2 * bj[i] + 1;
        cb_best[w][lane + 64 * i] = best[i];
        cb_bi[w][lane + 64 * i]   = bi;
    }
    __syncthreads();

    // Combine quarters (ordered strict < => numpy first-index), write, loss.
    // px p = t was scanned by THIS thread at slot i == w: reuse regs, no z re-read.
    f2 zA = ZA[0], zB = ZB[0];
    if (w == 1)      { zA = ZA[1]; zB = ZB[1]; }
    else if (w == 2) { zA = ZA[2]; zB = ZB[2]; }
    else if (w == 3) { zA = ZA[3]; zB = ZB[3]; }

    float lsum = 0.0f;
    {
        const int p = t;                      // 0..255 within block
        float bb = cb_best[0][p];
        int   kk = cb_bi[0][p];
#pragma unroll
        for (int ww = 1; ww < NWAVE; ++ww) {
            const float d  = cb_best[ww][p];
            const int   k2 = cb_bi[ww][p];
            if (d < bb) { bb = d; kk = k2; }
        }
        const int base = b * CHW + p0 + p;
        const float c0 = table[3 * kk + 0];
        const float c1 = table[3 * kk + 1];
        const float c2 = table[3 * kk + 2];
        out[base]          = c0;
        out[base + HW]     = c1;
        out[base + 2 * HW] = c2;
        const float e0 = c0 - zA.x, e1 = c1 - zA.y, e2 = c2 - zB.x;
        lsum = e0 * e0 + e1 * e1 + e2 * e2;
    }

    for (int off = 32; off > 0; off >>= 1)
        lsum += __shfl_down(lsum, off);

    if ((t & 63) == 0) wsum[w] = lsum;
    __syncthreads();
    if (t == 0) {
        const float s = wsum[0] + wsum[1] + wsum[2] + wsum[3];
        atomicAdd(loss, s * (11.0f / (float)NELEM));
    }
}

extern "C" void kernel_launch(void* const* d_in, const int* in_sizes, int n_in,
                              void* d_out, int out_size, void* d_ws, size_t ws_size,
                              hipStream_t stream)
{
    const float* z     = (const float*)d_in[0];
    const float* table = (const float*)d_in[1];
    float* out  = (float*)d_out;
    float* loss = out + NELEM;

    hipMemsetAsync(loss, 0, sizeof(float), stream);
    vq_kernel<<<NPIX / 256, 256, 0, stream>>>(z, table, out, loss);
}